// Round 7
// baseline (114.587 us; speedup 1.0000x reference)
//
#include <hip/hip_runtime.h>
#include <cstdint>
#include <math.h>

#pragma clang fp contract(off)

// Canny_1116691497316: per-channel Canny edges, out = x[:,indices] * tf
// x: (1,64,512,512) f32, indices: (32,) int32, out: (1,32,512,512) f32
//
// All decision variables in f64 (matches numpy f64 oracle; rounds 4-6 absmax 0.0).
// Round 7: canny_fused made ~2.3x leaner — separable blur (two LDS passes),
// sqrt eliminated (compare mag^2 against squared thresholds / neighbors),
// sector axis computed once in the mag pass (u8 LDS tile).
// Pipeline: canny_fused -> hyst_iterate -> mul. d_ws = 2 MB bitmaps.

constexpr int HH = 512;
constexpr int WW = 512;
constexpr int HW = HH * WW;          // 262144 px per channel
constexpr int KCH = 32;              // selected channels
constexpr int WORDS = HW / 32;       // 8192 uint32 words per bitmap per channel

constexpr int TY = 32;               // output tile rows
constexpr int TX = 64;               // output tile cols
constexpr int NTY = HH / TY;         // 16
constexpr int NTX = WW / TX;         // 8

// f64 gaussian weights, exact value chain of the reference:
// g_i = exp(-0.5*t^2), s = ((((g0+g1)+g2)+g3)+g4), w_i = g_i/s (IEEE f64)
constexpr double E2 = 0.13533528323661269189;  // exp(-2.0), correctly rounded
constexpr double E1 = 0.60653065971263342360;  // exp(-0.5), correctly rounded
constexpr double GS = ((((E2 + E1) + 1.0) + E1) + E2);
constexpr double GW0 = E2 / GS, GW1 = E1 / GS, GW2 = 1.0 / GS;

// tan(22.5deg) = sqrt(2)-1, tan(67.5deg) = sqrt(2)+1
constexpr double T1 = 0.4142135623730950488;
constexpr double T2 = 2.4142135623730950488;

// squared thresholds: m > 0.2  <=>  m^2 > (0.2)^2 up to ~1-ulp sqrt band
constexpr double SQ_HI = 0.2 * 0.2;
constexpr double SQ_LO = 0.1 * 0.1;

__device__ __forceinline__ int reflect_idx(int v) {
    // jnp.pad mode='reflect', N=512 (valid for overhang <= 4 here)
    return v < 0 ? -v : (v > 511 ? 1022 - v : v);
}
__device__ __forceinline__ int clampi(int v) {
    return v < 0 ? 0 : (v > 511 ? 511 : v);
}

// axis a in {0..3}: NMS neighbor pair, == rint(atan2(gy,gx)*(180/pi)/45) mod 4
__device__ const int AY1[4] = {0, 1, 1, 1};
__device__ const int AX1[4] = {1, 1, 0, -1};

// ---------------- Kernel 1: fused blur + sobel + mag^2 + NMS + thresholds ----------------
// One 256-thread block per 32x64 output tile.
// LDS: in_s f32 [40][72] (halo 4) | vp_s f64 [36*72] vertical-blur pass,
// overlaid by sq_s f64 [34*66] after use | bl_s f64 [36][68] | ax_s u8 [32][64].
// Total 53,888 B -> 3 blocks/CU.
__global__ __launch_bounds__(256) void canny_fused(const float* __restrict__ x,
                                                   const int* __restrict__ idx,
                                                   unsigned long long* __restrict__ weakb,
                                                   unsigned long long* __restrict__ strongb) {
    #pragma clang fp contract(off)
    __shared__ float  in_s[TY + 8][TX + 8];        // [40][72]
    __shared__ double vp_s[(TY + 4) * (TX + 8)];   // [36*72]; later sq_s [34*66]
    __shared__ double bl_s[TY + 4][TX + 4];        // [36][68]
    __shared__ unsigned char ax_s[TY][TX];         // [32][64]
    double* sq_s = vp_s;                            // overlay (after hpass barrier)

    int tile = blockIdx.x;
    int k = tile >> 7;                 // 128 tiles per channel
    int t = tile & 127;
    int ty0 = (t >> 3) * TY;           // 16 row-tiles
    int tx0 = (t & 7) * TX;            // 8 col-tiles
    int tid = threadIdx.x;

    int ch = idx[k];
    const float* img = x + (size_t)ch * HW;

    // ---- load input tile (reflect-mapped == reference's pad-then-conv) ----
    for (int i = tid; i < (TY + 8) * (TX + 8); i += 256) {
        int a = i / (TX + 8), b = i - a * (TX + 8);
        int gy = reflect_idx(ty0 - 4 + a);
        int gx = reflect_idx(tx0 - 4 + b);
        in_s[a][b] = img[gy * WW + gx];
    }
    __syncthreads();

    const double g[5] = {GW0, GW1, GW2, GW1, GW0};

    // ---- vertical blur pass: vp(a,b) = sum_j g[j]*in[a+j][b], 36x72 ----
    for (int c = tid; c < (TY + 4) * (TX + 8); c += 256) {
        int a = c / (TX + 8), b = c - a * (TX + 8);
        double acc = 0.0;
        #pragma unroll
        for (int j = 0; j < 5; j++) {
            acc += g[j] * (double)in_s[a + j][b];
        }
        vp_s[c] = acc;
    }
    __syncthreads();

    // ---- horizontal blur pass: bl(a,b) = sum_i g[i]*vp(a,b+i), 36x68 ----
    for (int c = tid; c < (TY + 4) * (TX + 4); c += 256) {
        int a = c / (TX + 4), b = c - a * (TX + 4);
        double acc = 0.0;
        #pragma unroll
        for (int i = 0; i < 5; i++) {
            acc += g[i] * vp_s[a * (TX + 8) + b + i];
        }
        bl_s[a][b] = acc;
    }
    __syncthreads();   // also fences vp reads before sq overlay writes

    // ---- mag^2 + axis: sobel (replicate-clamped) on bl, 34x66 ----
    for (int c = tid; c < (TY + 2) * (TX + 2); c += 256) {
        int am = c / (TX + 2), bm = c - am * (TX + 2);
        int u = ty0 - 1 + am, v = tx0 - 1 + bm;       // global coords
        int ru = clampi(u - 1) - (ty0 - 2);
        int r0 = u - (ty0 - 2);
        int rd = clampi(u + 1) - (ty0 - 2);
        int cl = clampi(v - 1) - (tx0 - 2);
        int c0 = v - (tx0 - 2);
        int cr = clampi(v + 1) - (tx0 - 2);
        double v00 = bl_s[ru][cl], v01 = bl_s[ru][c0], v02 = bl_s[ru][cr];
        double v10 = bl_s[r0][cl],                      v12 = bl_s[r0][cr];
        double v20 = bl_s[rd][cl], v21 = bl_s[rd][c0], v22 = bl_s[rd][cr];
        double gxv = ((((-v00 + v02) + (-2.0 * v10)) + (2.0 * v12)) + (-v20)) + v22;
        double gyv = ((((-v00 + (-2.0 * v01)) + (-v02)) + v20) + (2.0 * v21)) + v22;
        sq_s[c] = (gxv * gxv + gyv * gyv) + 1e-6;     // c == am*66+bm

        // sector: fold gy<0; compare |gy| vs tan boundaries (round-5/6 logic)
        double axv = fabs(gxv), ayv = fabs(gyv);
        int axis;
        if (ayv < T1 * axv) axis = 0;
        else if (ayv > T2 * axv) axis = 2;
        else {
            double gxf = (gyv < 0.0) ? -gxv : gxv;
            axis = (gxf > 0.0) ? 1 : 3;
        }
        if (am >= 1 && am <= TY && bm >= 1 && bm <= TX)
            ax_s[am - 1][bm - 1] = (unsigned char)axis;
    }
    __syncthreads();

    // ---- NMS + double threshold + ballot (squared domain) ----
    for (int q8 = 0; q8 < TY * TX / 256; q8++) {
        int l = q8 * 256 + tid;
        int oy = l >> 6, ox = l & 63;                 // wave = one 64-px row span
        int gy = ty0 + oy, gx = tx0 + ox;

        int axis = ax_s[oy][ox];
        int dy = AY1[axis], dx = AX1[axis];
        double s = sq_s[(oy + 1) * (TX + 2) + (ox + 1)];

        int y1 = gy + dy, x1 = gx + dx;
        int y2 = gy - dy, x2 = gx - dx;
        // NMS conv zero-padded: out-of-image neighbor contributes 0
        double s1 = (y1 >= 0 && y1 < HH && x1 >= 0 && x1 < WW)
                        ? sq_s[(oy + 1 + dy) * (TX + 2) + (ox + 1 + dx)] : 0.0;
        double s2 = (y2 >= 0 && y2 < HH && x2 >= 0 && x2 < WW)
                        ? sq_s[(oy + 1 - dy) * (TX + 2) + (ox + 1 - dx)] : 0.0;
        bool keep = (s > s1) && (s > s2);

        bool strong = keep && (s > SQ_HI);
        bool weak = keep && (s > SQ_LO) && !strong;

        unsigned long long wb = __ballot(weak);
        unsigned long long sb = __ballot(strong);
        if ((tid & 63) == 0) {
            size_t w64 = ((size_t)k * HW + (size_t)gy * WW + tx0) >> 6;
            weakb[w64] = wb;
            strongb[w64] = sb;
        }
    }
}

// ---------------- Kernel 2: hysteresis closure on bitmaps ----------------
// One block per channel; strong bitmap in LDS; monotone 3x3 bitwise dilation
// through the weak mask until fixed point (== reference while_loop fixed point).
__global__ __launch_bounds__(1024) void hyst_iterate(const unsigned int* __restrict__ weakb,
                                                     unsigned int* __restrict__ strongb) {
    int k = blockIdx.x;
    __shared__ unsigned int Sm[WORDS];
    __shared__ int s_changed;
    int tid = threadIdx.x;

    const unsigned int* wsrc = weakb + (size_t)k * WORDS;
    unsigned int* ssrc = strongb + (size_t)k * WORDS;

    if (tid == 0) s_changed = 0;
    for (int i = tid; i < WORDS; i += 1024) Sm[i] = ssrc[i];
    unsigned int wreg[8];
    #pragma unroll
    for (int q = 0; q < 8; q++) wreg[q] = wsrc[tid * 8 + q];
    __syncthreads();

    for (;;) {
        int loc = 0;
        #pragma unroll
        for (int q = 0; q < 8; q++) {
            int w = tid * 8 + q;
            unsigned int s = Sm[w];
            unsigned int wk = wreg[q] & ~s;
            if (!wk) continue;
            int j = w & 15;  // word column within 16-word row
            unsigned int L = j ? Sm[w - 1] : 0u;
            unsigned int R = (j < 15) ? Sm[w + 1] : 0u;
            unsigned int D = (s << 1) | (L >> 31) | (s >> 1) | (R << 31);
            if (w >= 16) {
                unsigned int cu = Sm[w - 16];
                unsigned int Lu = j ? Sm[w - 17] : 0u;
                unsigned int Ru = (j < 15) ? Sm[w - 15] : 0u;
                D |= cu | (cu << 1) | (Lu >> 31) | (cu >> 1) | (Ru << 31);
            }
            if (w < WORDS - 16) {
                unsigned int cd = Sm[w + 16];
                unsigned int Ld = j ? Sm[w + 15] : 0u;
                unsigned int Rd = (j < 15) ? Sm[w + 17] : 0u;
                D |= cd | (cd << 1) | (Ld >> 31) | (cd >> 1) | (Rd << 31);
            }
            unsigned int promoted = wk & D;
            if (promoted) { Sm[w] = s | promoted; loc = 1; }
        }
        if (loc) s_changed = 1;
        __syncthreads();
        int chg = s_changed;
        __syncthreads();
        if (!chg) break;
        if (tid == 0) s_changed = 0;
        __syncthreads();
    }

    for (int i = tid; i < WORDS; i += 1024) ssrc[i] = Sm[i];
}

// ---------------- Kernel 3: out = x[:,indices] * tf, full grid, float4 ----------------
__global__ void mul_kernel(const float* __restrict__ x,
                           const int* __restrict__ idx,
                           const unsigned int* __restrict__ weakb,
                           const unsigned int* __restrict__ strongb,
                           float* __restrict__ out) {
    int gid = blockIdx.x * blockDim.x + threadIdx.x;
    int p = gid * 4;
    if (p >= KCH * HW) return;
    int k = p >> 18;
    int r = p & (HW - 1);
    int ch = idx[k];

    unsigned int sw = strongb[p >> 5];
    unsigned int ww = weakb[p >> 5];
    int b0 = p & 31;

    const float4 xv = *reinterpret_cast<const float4*>(x + (size_t)ch * HW + r);
    float t[4];
    #pragma unroll
    for (int i = 0; i < 4; i++) {
        int b = b0 + i;
        t[i] = ((sw >> b) & 1u) ? 1.0f : (((ww >> b) & 1u) ? 0.5f : 0.0f);
    }
    float4 o;
    o.x = xv.x * t[0];
    o.y = xv.y * t[1];
    o.z = xv.z * t[2];
    o.w = xv.w * t[3];
    *reinterpret_cast<float4*>(out + (size_t)p) = o;
}

extern "C" void kernel_launch(void* const* d_in, const int* in_sizes, int n_in,
                              void* d_out, int out_size, void* d_ws, size_t ws_size,
                              hipStream_t stream) {
    const float* x = (const float*)d_in[0];
    // d_in[1] = params (always 1 here; params==0 changes output shape, impossible
    // given out_size)
    const int* idx = (const int*)d_in[2];
    float* out = (float*)d_out;

    char* ws = (char*)d_ws;
    unsigned long long* weakb = (unsigned long long*)ws;                 // 1 MB
    unsigned long long* strongb = (unsigned long long*)(ws + 1048576);   // 1 MB

    int ntiles = KCH * NTY * NTX;  // 32 * 128 = 4096
    canny_fused<<<ntiles, 256, 0, stream>>>(x, idx, weakb, strongb);
    hyst_iterate<<<KCH, 1024, 0, stream>>>((const unsigned int*)weakb,
                                           (unsigned int*)strongb);
    mul_kernel<<<(KCH * HW / 4) / 256, 256, 0, stream>>>(x, idx,
                                                         (const unsigned int*)weakb,
                                                         (const unsigned int*)strongb,
                                                         out);
}

// Round 8
// 71.114 us; speedup vs baseline: 1.6113x; 1.6113x over previous
//
#include <hip/hip_runtime.h>
#include <cstdint>
#include <math.h>

#pragma clang fp contract(off)

// Canny_1116691497316: per-channel Canny edges, out = x[:,indices] * tf
// x: (1,64,512,512) f32, indices: (32,) int32, out: (1,32,512,512) f32
//
// All decision variables in f64 (matches numpy f64 oracle; rounds 4-7 absmax 0.0).
// Round 8: occupancy fix. 32x32 tiles + LDS lifetime overlay -> 22,912 B/block
// (was 54,272) -> up to 7 blocks/CU (was 2). Same lean math as round 7
// (separable blur, squared-mag comparisons, precomputed axis).
// Pipeline: canny_fused -> hyst_iterate -> mul. d_ws = 2 MB bitmaps.

constexpr int HH = 512;
constexpr int WW = 512;
constexpr int HW = HH * WW;          // 262144 px per channel
constexpr int KCH = 32;              // selected channels
constexpr int WORDS = HW / 32;       // 8192 uint32 words per bitmap per channel

constexpr int TD = 32;               // tile dim (32x32 output px)
constexpr int NT = HH / TD;          // 16 tiles per side, 256 per channel

// LDS region sizes (bytes)
constexpr int IN_D = TD + 8;         // 40
constexpr int VP_R = TD + 4;         // 36 rows
constexpr int VP_C = TD + 8;         // 40 cols
constexpr int BL_D = TD + 4;         // 36
constexpr int SQ_D = TD + 2;         // 34

// f64 gaussian weights, exact value chain of the reference:
// g_i = exp(-0.5*t^2), s = ((((g0+g1)+g2)+g3)+g4), w_i = g_i/s (IEEE f64)
constexpr double E2 = 0.13533528323661269189;  // exp(-2.0), correctly rounded
constexpr double E1 = 0.60653065971263342360;  // exp(-0.5), correctly rounded
constexpr double GS = ((((E2 + E1) + 1.0) + E1) + E2);
constexpr double GW0 = E2 / GS, GW1 = E1 / GS, GW2 = 1.0 / GS;

// tan(22.5deg) = sqrt(2)-1, tan(67.5deg) = sqrt(2)+1
constexpr double T1 = 0.4142135623730950488;
constexpr double T2 = 2.4142135623730950488;

// squared thresholds: m > thr  <=>  m^2 > thr^2 (up to ~1-ulp sqrt band)
constexpr double SQ_HI = 0.2 * 0.2;
constexpr double SQ_LO = 0.1 * 0.1;

__device__ __forceinline__ int reflect_idx(int v) {
    // jnp.pad mode='reflect', N=512 (valid for overhang <= 4 here)
    return v < 0 ? -v : (v > 511 ? 1022 - v : v);
}
__device__ __forceinline__ int clampi(int v) {
    return v < 0 ? 0 : (v > 511 ? 511 : v);
}

// axis a in {0..3}: NMS neighbor pair, == rint(atan2(gy,gx)*(180/pi)/45) mod 4
__device__ const int AY1[4] = {0, 1, 1, 1};
__device__ const int AX1[4] = {1, 1, 0, -1};

// ---------------- Kernel 1: fused blur + sobel + mag^2 + NMS + thresholds ----------------
// One 256-thread block per 32x32 output tile. LDS overlay (22,912 B):
//   region0 [0, 11520):      vp f64[36][40]  -> later sq f64[34][34] (9248 B)
//   region1 [11520, 21888):  bl f64[36][36]  <- earlier in f32[40][40] (6400 B)
//   region2 [21888, 22912):  ax u8[32][32]
__global__ __launch_bounds__(256) void canny_fused(const float* __restrict__ x,
                                                   const int* __restrict__ idx,
                                                   unsigned int* __restrict__ weakb,
                                                   unsigned int* __restrict__ strongb) {
    #pragma clang fp contract(off)
    __shared__ __align__(16) char lds[22912];
    double* vp_s = (double*)lds;                           // [36*40]
    double* sq_s = (double*)lds;                           // [34*34] overlay (vp dead)
    double* bl_s = (double*)(lds + 11520);                 // [36*36]
    float*  in_s = (float*)(lds + 11520);                  // [40*40] overlay (dies before bl)
    unsigned char* ax_s = (unsigned char*)(lds + 21888);   // [32*32]

    int tile = blockIdx.x;
    int k = tile >> 8;                 // 256 tiles per channel
    int t = tile & 255;
    int ty0 = (t >> 4) * TD;
    int tx0 = (t & 15) * TD;
    int tid = threadIdx.x;

    int ch = idx[k];
    const float* img = x + (size_t)ch * HW;

    // ---- load input tile 40x40 (reflect-mapped == reference pad-then-conv) ----
    for (int i = tid; i < IN_D * IN_D; i += 256) {
        int a = i / IN_D, b = i - a * IN_D;
        int gy = reflect_idx(ty0 - 4 + a);
        int gx = reflect_idx(tx0 - 4 + b);
        in_s[i] = img[gy * WW + gx];
    }
    __syncthreads();

    const double g[5] = {GW0, GW1, GW2, GW1, GW0};

    // ---- vertical blur pass: vp(a,b) = sum_j g[j]*in[a+j][b], 36x40 ----
    for (int c = tid; c < VP_R * VP_C; c += 256) {
        int a = c / VP_C, b = c - a * VP_C;
        double acc = 0.0;
        #pragma unroll
        for (int j = 0; j < 5; j++) {
            acc += g[j] * (double)in_s[(a + j) * IN_D + b];
        }
        vp_s[c] = acc;
    }
    __syncthreads();

    // ---- horizontal blur pass: bl(a,b) = sum_i g[i]*vp(a,b+i), 36x36 ----
    // (bl overlays in_s, which is dead after the vp pass)
    for (int c = tid; c < BL_D * BL_D; c += 256) {
        int a = c / BL_D, b = c - a * BL_D;
        double acc = 0.0;
        #pragma unroll
        for (int i = 0; i < 5; i++) {
            acc += g[i] * vp_s[a * VP_C + b + i];
        }
        bl_s[c] = acc;
    }
    __syncthreads();   // fences vp reads before sq overlay writes

    // ---- mag^2 + axis: sobel (replicate-clamped) on bl, 34x34 ----
    for (int c = tid; c < SQ_D * SQ_D; c += 256) {
        int am = c / SQ_D, bm = c - am * SQ_D;
        int u = ty0 - 1 + am, v = tx0 - 1 + bm;       // global coords
        int ru = clampi(u - 1) - (ty0 - 2);
        int r0 = am + 1;                               // u - (ty0-2)
        int rd = clampi(u + 1) - (ty0 - 2);
        int cl = clampi(v - 1) - (tx0 - 2);
        int c0 = bm + 1;
        int cr = clampi(v + 1) - (tx0 - 2);
        double v00 = bl_s[ru * BL_D + cl], v01 = bl_s[ru * BL_D + c0], v02 = bl_s[ru * BL_D + cr];
        double v10 = bl_s[r0 * BL_D + cl],                              v12 = bl_s[r0 * BL_D + cr];
        double v20 = bl_s[rd * BL_D + cl], v21 = bl_s[rd * BL_D + c0], v22 = bl_s[rd * BL_D + cr];
        double gxv = ((((-v00 + v02) + (-2.0 * v10)) + (2.0 * v12)) + (-v20)) + v22;
        double gyv = ((((-v00 + (-2.0 * v01)) + (-v02)) + v20) + (2.0 * v21)) + v22;
        sq_s[c] = (gxv * gxv + gyv * gyv) + 1e-6;

        // sector: fold gy<0; compare |gy| vs tan boundaries (rounds 5-7 logic)
        double axv = fabs(gxv), ayv = fabs(gyv);
        int axis;
        if (ayv < T1 * axv) axis = 0;
        else if (ayv > T2 * axv) axis = 2;
        else {
            double gxf = (gyv < 0.0) ? -gxv : gxv;
            axis = (gxf > 0.0) ? 1 : 3;
        }
        if (am >= 1 && am <= TD && bm >= 1 && bm <= TD)
            ax_s[(am - 1) * TD + (bm - 1)] = (unsigned char)axis;
    }
    __syncthreads();

    // ---- NMS + double threshold + ballot (squared domain) ----
    // 64-lane wave spans 2 image rows x 32 cols; write ballots as two u32 halves.
    for (int q4 = 0; q4 < TD * TD / 256; q4++) {
        int l = q4 * 256 + tid;
        int oy = l >> 5, ox = l & 31;
        int gy = ty0 + oy, gx = tx0 + ox;

        int axis = ax_s[oy * TD + ox];
        int dy = AY1[axis], dx = AX1[axis];
        double s = sq_s[(oy + 1) * SQ_D + (ox + 1)];

        int y1 = gy + dy, x1 = gx + dx;
        int y2 = gy - dy, x2 = gx - dx;
        // NMS conv zero-padded: out-of-image neighbor contributes 0
        double s1 = (y1 >= 0 && y1 < HH && x1 >= 0 && x1 < WW)
                        ? sq_s[(oy + 1 + dy) * SQ_D + (ox + 1 + dx)] : 0.0;
        double s2 = (y2 >= 0 && y2 < HH && x2 >= 0 && x2 < WW)
                        ? sq_s[(oy + 1 - dy) * SQ_D + (ox + 1 - dx)] : 0.0;
        bool keep = (s > s1) && (s > s2);

        bool strong = keep && (s > SQ_HI);
        bool weak = keep && (s > SQ_LO) && !strong;

        unsigned long long wb = __ballot(weak);
        unsigned long long sb = __ballot(strong);
        if ((tid & 31) == 0) {
            unsigned int ww = (tid & 32) ? (unsigned int)(wb >> 32) : (unsigned int)wb;
            unsigned int sw = (tid & 32) ? (unsigned int)(sb >> 32) : (unsigned int)sb;
            size_t w32 = ((size_t)k * HW + (size_t)gy * WW + tx0) >> 5;
            weakb[w32] = ww;
            strongb[w32] = sw;
        }
    }
}

// ---------------- Kernel 2: hysteresis closure on bitmaps ----------------
// One block per channel; strong bitmap in LDS; monotone 3x3 bitwise dilation
// through the weak mask until fixed point (== reference while_loop fixed point).
__global__ __launch_bounds__(1024) void hyst_iterate(const unsigned int* __restrict__ weakb,
                                                     unsigned int* __restrict__ strongb) {
    int k = blockIdx.x;
    __shared__ unsigned int Sm[WORDS];
    __shared__ int s_changed;
    int tid = threadIdx.x;

    const unsigned int* wsrc = weakb + (size_t)k * WORDS;
    unsigned int* ssrc = strongb + (size_t)k * WORDS;

    if (tid == 0) s_changed = 0;
    for (int i = tid; i < WORDS; i += 1024) Sm[i] = ssrc[i];
    unsigned int wreg[8];
    #pragma unroll
    for (int q = 0; q < 8; q++) wreg[q] = wsrc[tid * 8 + q];
    __syncthreads();

    for (;;) {
        int loc = 0;
        #pragma unroll
        for (int q = 0; q < 8; q++) {
            int w = tid * 8 + q;
            unsigned int s = Sm[w];
            unsigned int wk = wreg[q] & ~s;
            if (!wk) continue;
            int j = w & 15;  // word column within 16-word row
            unsigned int L = j ? Sm[w - 1] : 0u;
            unsigned int R = (j < 15) ? Sm[w + 1] : 0u;
            unsigned int D = (s << 1) | (L >> 31) | (s >> 1) | (R << 31);
            if (w >= 16) {
                unsigned int cu = Sm[w - 16];
                unsigned int Lu = j ? Sm[w - 17] : 0u;
                unsigned int Ru = (j < 15) ? Sm[w - 15] : 0u;
                D |= cu | (cu << 1) | (Lu >> 31) | (cu >> 1) | (Ru << 31);
            }
            if (w < WORDS - 16) {
                unsigned int cd = Sm[w + 16];
                unsigned int Ld = j ? Sm[w + 15] : 0u;
                unsigned int Rd = (j < 15) ? Sm[w + 17] : 0u;
                D |= cd | (cd << 1) | (Ld >> 31) | (cd >> 1) | (Rd << 31);
            }
            unsigned int promoted = wk & D;
            if (promoted) { Sm[w] = s | promoted; loc = 1; }
        }
        if (loc) s_changed = 1;
        __syncthreads();
        int chg = s_changed;
        __syncthreads();
        if (!chg) break;
        if (tid == 0) s_changed = 0;
        __syncthreads();
    }

    for (int i = tid; i < WORDS; i += 1024) ssrc[i] = Sm[i];
}

// ---------------- Kernel 3: out = x[:,indices] * tf, full grid, float4 ----------------
__global__ void mul_kernel(const float* __restrict__ x,
                           const int* __restrict__ idx,
                           const unsigned int* __restrict__ weakb,
                           const unsigned int* __restrict__ strongb,
                           float* __restrict__ out) {
    int gid = blockIdx.x * blockDim.x + threadIdx.x;
    int p = gid * 4;
    if (p >= KCH * HW) return;
    int k = p >> 18;
    int r = p & (HW - 1);
    int ch = idx[k];

    unsigned int sw = strongb[p >> 5];
    unsigned int ww = weakb[p >> 5];
    int b0 = p & 31;

    const float4 xv = *reinterpret_cast<const float4*>(x + (size_t)ch * HW + r);
    float t[4];
    #pragma unroll
    for (int i = 0; i < 4; i++) {
        int b = b0 + i;
        t[i] = ((sw >> b) & 1u) ? 1.0f : (((ww >> b) & 1u) ? 0.5f : 0.0f);
    }
    float4 o;
    o.x = xv.x * t[0];
    o.y = xv.y * t[1];
    o.z = xv.z * t[2];
    o.w = xv.w * t[3];
    *reinterpret_cast<float4*>(out + (size_t)p) = o;
}

extern "C" void kernel_launch(void* const* d_in, const int* in_sizes, int n_in,
                              void* d_out, int out_size, void* d_ws, size_t ws_size,
                              hipStream_t stream) {
    const float* x = (const float*)d_in[0];
    // d_in[1] = params (always 1 here; params==0 changes output shape, impossible
    // given out_size)
    const int* idx = (const int*)d_in[2];
    float* out = (float*)d_out;

    char* ws = (char*)d_ws;
    unsigned int* weakb = (unsigned int*)ws;                 // 1 MB
    unsigned int* strongb = (unsigned int*)(ws + 1048576);   // 1 MB

    int ntiles = KCH * NT * NT;  // 32 * 256 = 8192
    canny_fused<<<ntiles, 256, 0, stream>>>(x, idx, weakb, strongb);
    hyst_iterate<<<KCH, 1024, 0, stream>>>(weakb, strongb);
    mul_kernel<<<(KCH * HW / 4) / 256, 256, 0, stream>>>(x, idx, weakb, strongb, out);
}

// Round 10
// 69.280 us; speedup vs baseline: 1.6540x; 1.0265x over previous
//
#include <hip/hip_runtime.h>
#include <cstdint>
#include <math.h>

// NOTE: fp contraction deliberately ENABLED (round 9): f64 FMA differs from
// mul+add by ~1 ulp (1e-16 rel); decision-flip probability ~1e-13 total.

// Canny_1116691497316: per-channel Canny edges, out = x[:,indices] * tf
// x: (1,64,512,512) f32, indices: (32,) int32, out: (1,32,512,512) f32
//
// All decision variables in f64 (matches numpy f64 oracle; rounds 4-8 absmax 0.0).
// Round 10: round 9 + the missing __syncthreads() between LDS index-table
// writes and the table-consuming input load (cross-wave race -> absmax 4.03).
// Pipeline: canny_fused -> hyst_iterate -> mul. d_ws = 2 MB bitmaps.

constexpr int HH = 512;
constexpr int WW = 512;
constexpr int HW = HH * WW;          // 262144 px per channel
constexpr int KCH = 32;              // selected channels
constexpr int WORDS = HW / 32;       // 8192 uint32 words per bitmap per channel

constexpr int TD = 32;               // tile dim (32x32 output px)
constexpr int NT = HH / TD;          // 16 tiles per side, 256 per channel

constexpr int IN_D = 40;             // input tile 40x40 (halo 4)
constexpr int VP_R = 36, VP_C = 40;  // vertical-blur pass tile
constexpr int BL_D = 36;             // blur tile 36x36 (halo 2)
constexpr int SQ_D = 34;             // mag^2 tile 34x34 (halo 1)

// f64 gaussian weights, exact value chain of the reference:
// g_i = exp(-0.5*t^2), s = ((((g0+g1)+g2)+g3)+g4), w_i = g_i/s (IEEE f64)
constexpr double E2 = 0.13533528323661269189;  // exp(-2.0), correctly rounded
constexpr double E1 = 0.60653065971263342360;  // exp(-0.5), correctly rounded
constexpr double GS = ((((E2 + E1) + 1.0) + E1) + E2);
constexpr double GW0 = E2 / GS, GW1 = E1 / GS, GW2 = 1.0 / GS;

// tan(22.5deg) = sqrt(2)-1, tan(67.5deg) = sqrt(2)+1
constexpr double T1 = 0.4142135623730950488;
constexpr double T2 = 2.4142135623730950488;

// squared thresholds: m > thr  <=>  m^2 > thr^2 (up to ~1-ulp sqrt band)
constexpr double SQ_HI = 0.2 * 0.2;
constexpr double SQ_LO = 0.1 * 0.1;

__device__ __forceinline__ int reflect_idx(int v) {
    // jnp.pad mode='reflect', N=512 (valid for overhang <= 4 here)
    return v < 0 ? -v : (v > 511 ? 1022 - v : v);
}
__device__ __forceinline__ int clampi(int v) {
    return v < 0 ? 0 : (v > 511 ? 511 : v);
}

// axis a in {0..3}: NMS neighbor pair, == rint(atan2(gy,gx)*(180/pi)/45) mod 4
__device__ const int AY1[4] = {0, 1, 1, 1};
__device__ const int AX1[4] = {1, 1, 0, -1};

// ---------------- Kernel 1: fused blur + sobel + mag^2 + NMS + thresholds ----------------
// One 256-thread block per 32x32 output tile. LDS overlay (23,296 B):
//   [0, 11520):      vp f64[36][40] -> later sq f64[34][34] overlay
//   [11520, 21888):  in f32[40][40] -> later bl f64[36][36] overlay
//   [21888, 22912):  ax u8[32][32]
//   [22912, 23208):  tables RU/RD/CL/CR u8[34] x4, rmap/cmap u16[40] x2
__global__ __launch_bounds__(256) void canny_fused(const float* __restrict__ x,
                                                   const int* __restrict__ idx,
                                                   unsigned int* __restrict__ weakb,
                                                   unsigned int* __restrict__ strongb) {
    __shared__ __align__(16) char lds[23296];
    double* vp_s = (double*)lds;                           // [36*40]
    double* sq_s = (double*)lds;                           // [34*34] overlay (vp dead)
    float*  in_s = (float*)(lds + 11520);                  // [40*40]
    double* bl_s = (double*)(lds + 11520);                 // [36*36] overlay (in dead)
    unsigned char* ax_s = (unsigned char*)(lds + 21888);   // [32*32]
    unsigned char* RUm = (unsigned char*)(lds + 22912);    // [34]
    unsigned char* RDm = RUm + 34;                         // [34]
    unsigned char* CLm = RUm + 68;                         // [34]
    unsigned char* CRm = RUm + 102;                        // [34]
    unsigned short* rmap = (unsigned short*)(lds + 23048); // [40]
    unsigned short* cmap = rmap + 40;                      // [40]

    int tile = blockIdx.x;
    int k = tile >> 8;                 // 256 tiles per channel
    int t = tile & 255;
    int ty0 = (t >> 4) * TD;
    int tx0 = (t & 15) * TD;
    int tid = threadIdx.x;

    int ch = idx[k];
    const float* img = x + (size_t)ch * HW;

    // ---- index tables ----
    if (tid < 40) {
        rmap[tid] = (unsigned short)reflect_idx(ty0 - 4 + tid);
        cmap[tid] = (unsigned short)reflect_idx(tx0 - 4 + tid);
    } else if (tid >= 64 && tid < 98) {
        int am = tid - 64;
        int u = ty0 - 1 + am;
        RUm[am] = (unsigned char)(clampi(u - 1) - (ty0 - 2));
        RDm[am] = (unsigned char)(clampi(u + 1) - (ty0 - 2));
    } else if (tid >= 128 && tid < 162) {
        int bm = tid - 128;
        int v = tx0 - 1 + bm;
        CLm[bm] = (unsigned char)(clampi(v - 1) - (tx0 - 2));
        CRm[bm] = (unsigned char)(clampi(v + 1) - (tx0 - 2));
    }
    __syncthreads();   // ROUND-10 FIX: load below consumes rmap/cmap cross-wave

    // ---- load input tile 40x40 via reflect maps ----
    {
        int a = tid / 40, b = tid - a * 40;   // one division
        while (a < 40) {
            in_s[a * IN_D + b] = img[(int)rmap[a] * WW + (int)cmap[b]];
            b += 16; a += 6;
            if (b >= 40) { b -= 40; a += 1; }
        }
    }
    __syncthreads();

    const double g[5] = {GW0, GW1, GW2, GW1, GW0};

    // ---- vertical blur: sliding window, 6 cells per thread along a column ----
    if (tid < 240) {
        int b = tid / 6;             // column 0..39
        int r = tid - 6 * b;         // 0..5
        int a0 = 6 * r;              // row group base
        double w[10];
        #pragma unroll
        for (int j = 0; j < 10; j++) w[j] = (double)in_s[(a0 + j) * IN_D + b];
        #pragma unroll
        for (int i = 0; i < 6; i++) {
            double acc = g[0] * w[i];
            acc += g[1] * w[i + 1];
            acc += g[2] * w[i + 2];
            acc += g[3] * w[i + 3];
            acc += g[4] * w[i + 4];
            vp_s[(a0 + i) * VP_C + b] = acc;
        }
    }
    __syncthreads();

    // ---- horizontal blur: sliding window, 6 cells per thread along a row ----
    // (bl overlays in_s, which is dead after the vertical pass)
    if (tid < 216) {
        int a = tid / 6;             // row 0..35
        int q = tid - 6 * a;         // 0..5
        int c0 = 6 * q;              // col group base
        double w[10];
        #pragma unroll
        for (int j = 0; j < 10; j++) w[j] = vp_s[a * VP_C + c0 + j];
        #pragma unroll
        for (int m = 0; m < 6; m++) {
            double acc = g[0] * w[m];
            acc += g[1] * w[m + 1];
            acc += g[2] * w[m + 2];
            acc += g[3] * w[m + 3];
            acc += g[4] * w[m + 4];
            bl_s[a * BL_D + c0 + m] = acc;
        }
    }
    __syncthreads();   // fences vp reads before sq overlay writes

    // ---- mag^2 + axis: sobel (clamp tables) on bl, 34x34 ----
    {
        int am = tid / 34, bm = tid - 34 * am;   // one division
        while (am < 34) {
            int ru = RUm[am], r0 = am + 1, rd = RDm[am];
            int cl = CLm[bm], c0 = bm + 1, cr = CRm[bm];
            double v00 = bl_s[ru * BL_D + cl], v01 = bl_s[ru * BL_D + c0], v02 = bl_s[ru * BL_D + cr];
            double v10 = bl_s[r0 * BL_D + cl],                              v12 = bl_s[r0 * BL_D + cr];
            double v20 = bl_s[rd * BL_D + cl], v21 = bl_s[rd * BL_D + c0], v22 = bl_s[rd * BL_D + cr];
            double gxv = ((((-v00 + v02) + (-2.0 * v10)) + (2.0 * v12)) + (-v20)) + v22;
            double gyv = ((((-v00 + (-2.0 * v01)) + (-v02)) + v20) + (2.0 * v21)) + v22;
            sq_s[am * SQ_D + bm] = (gxv * gxv + gyv * gyv) + 1e-6;

            // sector: fold gy<0; compare |gy| vs tan boundaries (rounds 5-8 logic)
            double axv = fabs(gxv), ayv = fabs(gyv);
            int axis;
            if (ayv < T1 * axv) axis = 0;
            else if (ayv > T2 * axv) axis = 2;
            else {
                double gxf = (gyv < 0.0) ? -gxv : gxv;
                axis = (gxf > 0.0) ? 1 : 3;
            }
            if (am >= 1 && am <= TD && bm >= 1 && bm <= TD)
                ax_s[(am - 1) * TD + (bm - 1)] = (unsigned char)axis;

            bm += 18; am += 7;                    // step 256 = 7*34 + 18
            if (bm >= 34) { bm -= 34; am += 1; }
        }
    }
    __syncthreads();

    // ---- NMS + double threshold + ballot (squared domain) ----
    // 64-lane wave spans 2 image rows x 32 cols; write ballots as two u32 halves.
    #pragma unroll
    for (int q4 = 0; q4 < TD * TD / 256; q4++) {
        int l = q4 * 256 + tid;
        int oy = l >> 5, ox = l & 31;
        int gy = ty0 + oy, gx = tx0 + ox;

        int axis = ax_s[oy * TD + ox];
        int dy = AY1[axis], dx = AX1[axis];
        double s = sq_s[(oy + 1) * SQ_D + (ox + 1)];

        int y1 = gy + dy, x1 = gx + dx;
        int y2 = gy - dy, x2 = gx - dx;
        // NMS conv zero-padded: out-of-image neighbor contributes 0
        double s1 = (y1 >= 0 && y1 < HH && x1 >= 0 && x1 < WW)
                        ? sq_s[(oy + 1 + dy) * SQ_D + (ox + 1 + dx)] : 0.0;
        double s2 = (y2 >= 0 && y2 < HH && x2 >= 0 && x2 < WW)
                        ? sq_s[(oy + 1 - dy) * SQ_D + (ox + 1 - dx)] : 0.0;
        bool keep = (s > s1) && (s > s2);

        bool strong = keep && (s > SQ_HI);
        bool weak = keep && (s > SQ_LO) && !strong;

        unsigned long long wb = __ballot(weak);
        unsigned long long sb = __ballot(strong);
        if ((tid & 31) == 0) {
            unsigned int ww = (tid & 32) ? (unsigned int)(wb >> 32) : (unsigned int)wb;
            unsigned int sw = (tid & 32) ? (unsigned int)(sb >> 32) : (unsigned int)sb;
            size_t w32 = ((size_t)k * HW + (size_t)gy * WW + tx0) >> 5;
            weakb[w32] = ww;
            strongb[w32] = sw;
        }
    }
}

// ---------------- Kernel 2: hysteresis closure on bitmaps ----------------
// One block per channel; strong bitmap in LDS; monotone 3x3 bitwise dilation
// through the weak mask until fixed point (== reference while_loop fixed point).
__global__ __launch_bounds__(1024) void hyst_iterate(const unsigned int* __restrict__ weakb,
                                                     unsigned int* __restrict__ strongb) {
    int k = blockIdx.x;
    __shared__ unsigned int Sm[WORDS];
    __shared__ int s_changed;
    int tid = threadIdx.x;

    const unsigned int* wsrc = weakb + (size_t)k * WORDS;
    unsigned int* ssrc = strongb + (size_t)k * WORDS;

    if (tid == 0) s_changed = 0;
    for (int i = tid; i < WORDS; i += 1024) Sm[i] = ssrc[i];
    unsigned int wreg[8];
    #pragma unroll
    for (int q = 0; q < 8; q++) wreg[q] = wsrc[tid * 8 + q];
    __syncthreads();

    for (;;) {
        int loc = 0;
        #pragma unroll
        for (int q = 0; q < 8; q++) {
            int w = tid * 8 + q;
            unsigned int s = Sm[w];
            unsigned int wk = wreg[q] & ~s;
            if (!wk) continue;
            int j = w & 15;  // word column within 16-word row
            unsigned int L = j ? Sm[w - 1] : 0u;
            unsigned int R = (j < 15) ? Sm[w + 1] : 0u;
            unsigned int D = (s << 1) | (L >> 31) | (s >> 1) | (R << 31);
            if (w >= 16) {
                unsigned int cu = Sm[w - 16];
                unsigned int Lu = j ? Sm[w - 17] : 0u;
                unsigned int Ru = (j < 15) ? Sm[w - 15] : 0u;
                D |= cu | (cu << 1) | (Lu >> 31) | (cu >> 1) | (Ru << 31);
            }
            if (w < WORDS - 16) {
                unsigned int cd = Sm[w + 16];
                unsigned int Ld = j ? Sm[w + 15] : 0u;
                unsigned int Rd = (j < 15) ? Sm[w + 17] : 0u;
                D |= cd | (cd << 1) | (Ld >> 31) | (cd >> 1) | (Rd << 31);
            }
            unsigned int promoted = wk & D;
            if (promoted) { Sm[w] = s | promoted; loc = 1; }
        }
        if (loc) s_changed = 1;
        __syncthreads();
        int chg = s_changed;
        __syncthreads();
        if (!chg) break;
        if (tid == 0) s_changed = 0;
        __syncthreads();
    }

    for (int i = tid; i < WORDS; i += 1024) ssrc[i] = Sm[i];
}

// ---------------- Kernel 3: out = x[:,indices] * tf, full grid, float4 ----------------
__global__ void mul_kernel(const float* __restrict__ x,
                           const int* __restrict__ idx,
                           const unsigned int* __restrict__ weakb,
                           const unsigned int* __restrict__ strongb,
                           float* __restrict__ out) {
    int gid = blockIdx.x * blockDim.x + threadIdx.x;
    int p = gid * 4;
    if (p >= KCH * HW) return;
    int k = p >> 18;
    int r = p & (HW - 1);
    int ch = idx[k];

    unsigned int sw = strongb[p >> 5];
    unsigned int ww = weakb[p >> 5];
    int b0 = p & 31;

    const float4 xv = *reinterpret_cast<const float4*>(x + (size_t)ch * HW + r);
    float t[4];
    #pragma unroll
    for (int i = 0; i < 4; i++) {
        int b = b0 + i;
        t[i] = ((sw >> b) & 1u) ? 1.0f : (((ww >> b) & 1u) ? 0.5f : 0.0f);
    }
    float4 o;
    o.x = xv.x * t[0];
    o.y = xv.y * t[1];
    o.z = xv.z * t[2];
    o.w = xv.w * t[3];
    *reinterpret_cast<float4*>(out + (size_t)p) = o;
}

extern "C" void kernel_launch(void* const* d_in, const int* in_sizes, int n_in,
                              void* d_out, int out_size, void* d_ws, size_t ws_size,
                              hipStream_t stream) {
    const float* x = (const float*)d_in[0];
    // d_in[1] = params (always 1 here; params==0 changes output shape, impossible
    // given out_size)
    const int* idx = (const int*)d_in[2];
    float* out = (float*)d_out;

    char* ws = (char*)d_ws;
    unsigned int* weakb = (unsigned int*)ws;                 // 1 MB
    unsigned int* strongb = (unsigned int*)(ws + 1048576);   // 1 MB

    int ntiles = KCH * NT * NT;  // 32 * 256 = 8192
    canny_fused<<<ntiles, 256, 0, stream>>>(x, idx, weakb, strongb);
    hyst_iterate<<<KCH, 1024, 0, stream>>>(weakb, strongb);
    mul_kernel<<<(KCH * HW / 4) / 256, 256, 0, stream>>>(x, idx, weakb, strongb, out);
}

// Round 11
// 67.677 us; speedup vs baseline: 1.6931x; 1.0237x over previous
//
#include <hip/hip_runtime.h>
#include <cstdint>
#include <math.h>

// fp contraction ENABLED (round 9+): f64 FMA vs mul+add differs ~1 ulp;
// decision-flip probability ~1e-13 total. Benched absmax 0.0 (round 10).

// Canny_1116691497316: per-channel Canny edges, out = x[:,indices] * tf
// x: (1,64,512,512) f32, indices: (32,) int32, out: (1,32,512,512) f32
//
// All decision variables in f64 (matches numpy f64 oracle; rounds 4-10 absmax 0.0).
// Round 11: LDS bank-conflict fix. Vertical blur remapped lane-major along
// columns (b = tid%40); horizontal blur back to per-cell linear (consecutive
// f64 reads). Same value chains as round 10.
// Pipeline: canny_fused -> hyst_iterate -> mul. d_ws = 2 MB bitmaps.

constexpr int HH = 512;
constexpr int WW = 512;
constexpr int HW = HH * WW;          // 262144 px per channel
constexpr int KCH = 32;              // selected channels
constexpr int WORDS = HW / 32;       // 8192 uint32 words per bitmap per channel

constexpr int TD = 32;               // tile dim (32x32 output px)
constexpr int NT = HH / TD;          // 16 tiles per side, 256 per channel

constexpr int IN_D = 40;             // input tile 40x40 (halo 4)
constexpr int VP_R = 36, VP_C = 40;  // vertical-blur pass tile
constexpr int BL_D = 36;             // blur tile 36x36 (halo 2)
constexpr int SQ_D = 34;             // mag^2 tile 34x34 (halo 1)

// f64 gaussian weights, exact value chain of the reference:
// g_i = exp(-0.5*t^2), s = ((((g0+g1)+g2)+g3)+g4), w_i = g_i/s (IEEE f64)
constexpr double E2 = 0.13533528323661269189;  // exp(-2.0), correctly rounded
constexpr double E1 = 0.60653065971263342360;  // exp(-0.5), correctly rounded
constexpr double GS = ((((E2 + E1) + 1.0) + E1) + E2);
constexpr double GW0 = E2 / GS, GW1 = E1 / GS, GW2 = 1.0 / GS;

// tan(22.5deg) = sqrt(2)-1, tan(67.5deg) = sqrt(2)+1
constexpr double T1 = 0.4142135623730950488;
constexpr double T2 = 2.4142135623730950488;

// squared thresholds: m > thr  <=>  m^2 > thr^2 (up to ~1-ulp sqrt band)
constexpr double SQ_HI = 0.2 * 0.2;
constexpr double SQ_LO = 0.1 * 0.1;

__device__ __forceinline__ int reflect_idx(int v) {
    // jnp.pad mode='reflect', N=512 (valid for overhang <= 4 here)
    return v < 0 ? -v : (v > 511 ? 1022 - v : v);
}
__device__ __forceinline__ int clampi(int v) {
    return v < 0 ? 0 : (v > 511 ? 511 : v);
}

// axis a in {0..3}: NMS neighbor pair, == rint(atan2(gy,gx)*(180/pi)/45) mod 4
__device__ const int AY1[4] = {0, 1, 1, 1};
__device__ const int AX1[4] = {1, 1, 0, -1};

// ---------------- Kernel 1: fused blur + sobel + mag^2 + NMS + thresholds ----------------
// One 256-thread block per 32x32 output tile. LDS overlay (23,296 B):
//   [0, 11520):      vp f64[36][40] -> later sq f64[34][34] overlay
//   [11520, 21888):  in f32[40][40] -> later bl f64[36][36] overlay
//   [21888, 22912):  ax u8[32][32]
//   [22912, 23208):  tables RU/RD/CL/CR u8[34] x4, rmap/cmap u16[40] x2
__global__ __launch_bounds__(256) void canny_fused(const float* __restrict__ x,
                                                   const int* __restrict__ idx,
                                                   unsigned int* __restrict__ weakb,
                                                   unsigned int* __restrict__ strongb) {
    __shared__ __align__(16) char lds[23296];
    double* vp_s = (double*)lds;                           // [36*40]
    double* sq_s = (double*)lds;                           // [34*34] overlay (vp dead)
    float*  in_s = (float*)(lds + 11520);                  // [40*40]
    double* bl_s = (double*)(lds + 11520);                 // [36*36] overlay (in dead)
    unsigned char* ax_s = (unsigned char*)(lds + 21888);   // [32*32]
    unsigned char* RUm = (unsigned char*)(lds + 22912);    // [34]
    unsigned char* RDm = RUm + 34;                         // [34]
    unsigned char* CLm = RUm + 68;                         // [34]
    unsigned char* CRm = RUm + 102;                        // [34]
    unsigned short* rmap = (unsigned short*)(lds + 23048); // [40]
    unsigned short* cmap = rmap + 40;                      // [40]

    int tile = blockIdx.x;
    int k = tile >> 8;                 // 256 tiles per channel
    int t = tile & 255;
    int ty0 = (t >> 4) * TD;
    int tx0 = (t & 15) * TD;
    int tid = threadIdx.x;

    int ch = idx[k];
    const float* img = x + (size_t)ch * HW;

    // ---- index tables ----
    if (tid < 40) {
        rmap[tid] = (unsigned short)reflect_idx(ty0 - 4 + tid);
        cmap[tid] = (unsigned short)reflect_idx(tx0 - 4 + tid);
    } else if (tid >= 64 && tid < 98) {
        int am = tid - 64;
        int u = ty0 - 1 + am;
        RUm[am] = (unsigned char)(clampi(u - 1) - (ty0 - 2));
        RDm[am] = (unsigned char)(clampi(u + 1) - (ty0 - 2));
    } else if (tid >= 128 && tid < 162) {
        int bm = tid - 128;
        int v = tx0 - 1 + bm;
        CLm[bm] = (unsigned char)(clampi(v - 1) - (tx0 - 2));
        CRm[bm] = (unsigned char)(clampi(v + 1) - (tx0 - 2));
    }
    __syncthreads();   // load below consumes rmap/cmap cross-wave

    // ---- load input tile 40x40 via reflect maps ----
    {
        int a = tid / 40, b = tid - a * 40;   // one division
        while (a < 40) {
            in_s[a * IN_D + b] = img[(int)rmap[a] * WW + (int)cmap[b]];
            b += 16; a += 6;
            if (b >= 40) { b -= 40; a += 1; }
        }
    }
    __syncthreads();

    const double g[5] = {GW0, GW1, GW2, GW1, GW0};

    // ---- vertical blur: sliding window, 6 cells/thread; lanes are
    //      CONSECUTIVE COLUMNS (bank-conflict-free reads & writes) ----
    if (tid < 240) {
        int rg = tid / 40;           // row group 0..5
        int b  = tid - 40 * rg;      // column 0..39 (lane-major)
        int a0 = 6 * rg;             // row base
        double w[10];
        #pragma unroll
        for (int j = 0; j < 10; j++) w[j] = (double)in_s[(a0 + j) * IN_D + b];
        #pragma unroll
        for (int i = 0; i < 6; i++) {
            double acc = g[0] * w[i];
            acc += g[1] * w[i + 1];
            acc += g[2] * w[i + 2];
            acc += g[3] * w[i + 3];
            acc += g[4] * w[i + 4];
            vp_s[(a0 + i) * VP_C + b] = acc;
        }
    }
    __syncthreads();

    // ---- horizontal blur: per-cell linear (consecutive f64 reads, no conflicts) ----
    // (bl overlays in_s, which is dead after the vertical pass)
    {
        int a = tid / 36, b = tid - 36 * (tid / 36);   // one division
        while (a < 36) {
            const double* vr = vp_s + a * VP_C + b;
            double acc = g[0] * vr[0];
            acc += g[1] * vr[1];
            acc += g[2] * vr[2];
            acc += g[3] * vr[3];
            acc += g[4] * vr[4];
            bl_s[a * BL_D + b] = acc;
            b += 4; a += 7;                            // step 256 = 7*36 + 4
            if (b >= 36) { b -= 36; a += 1; }
        }
    }
    __syncthreads();   // fences vp reads before sq overlay writes

    // ---- mag^2 + axis: sobel (clamp tables) on bl, 34x34 ----
    {
        int am = tid / 34, bm = tid - 34 * am;   // one division
        while (am < 34) {
            int ru = RUm[am], r0 = am + 1, rd = RDm[am];
            int cl = CLm[bm], c0 = bm + 1, cr = CRm[bm];
            double v00 = bl_s[ru * BL_D + cl], v01 = bl_s[ru * BL_D + c0], v02 = bl_s[ru * BL_D + cr];
            double v10 = bl_s[r0 * BL_D + cl],                              v12 = bl_s[r0 * BL_D + cr];
            double v20 = bl_s[rd * BL_D + cl], v21 = bl_s[rd * BL_D + c0], v22 = bl_s[rd * BL_D + cr];
            double gxv = ((((-v00 + v02) + (-2.0 * v10)) + (2.0 * v12)) + (-v20)) + v22;
            double gyv = ((((-v00 + (-2.0 * v01)) + (-v02)) + v20) + (2.0 * v21)) + v22;
            sq_s[am * SQ_D + bm] = (gxv * gxv + gyv * gyv) + 1e-6;

            // sector: fold gy<0; compare |gy| vs tan boundaries (rounds 5-10 logic)
            double axv = fabs(gxv), ayv = fabs(gyv);
            int axis;
            if (ayv < T1 * axv) axis = 0;
            else if (ayv > T2 * axv) axis = 2;
            else {
                double gxf = (gyv < 0.0) ? -gxv : gxv;
                axis = (gxf > 0.0) ? 1 : 3;
            }
            if (am >= 1 && am <= TD && bm >= 1 && bm <= TD)
                ax_s[(am - 1) * TD + (bm - 1)] = (unsigned char)axis;

            bm += 18; am += 7;                    // step 256 = 7*34 + 18
            if (bm >= 34) { bm -= 34; am += 1; }
        }
    }
    __syncthreads();

    // ---- NMS + double threshold + ballot (squared domain) ----
    // 64-lane wave spans 2 image rows x 32 cols; write ballots as two u32 halves.
    #pragma unroll
    for (int q4 = 0; q4 < TD * TD / 256; q4++) {
        int l = q4 * 256 + tid;
        int oy = l >> 5, ox = l & 31;
        int gy = ty0 + oy, gx = tx0 + ox;

        int axis = ax_s[oy * TD + ox];
        int dy = AY1[axis], dx = AX1[axis];
        double s = sq_s[(oy + 1) * SQ_D + (ox + 1)];

        int y1 = gy + dy, x1 = gx + dx;
        int y2 = gy - dy, x2 = gx - dx;
        // NMS conv zero-padded: out-of-image neighbor contributes 0
        double s1 = (y1 >= 0 && y1 < HH && x1 >= 0 && x1 < WW)
                        ? sq_s[(oy + 1 + dy) * SQ_D + (ox + 1 + dx)] : 0.0;
        double s2 = (y2 >= 0 && y2 < HH && x2 >= 0 && x2 < WW)
                        ? sq_s[(oy + 1 - dy) * SQ_D + (ox + 1 - dx)] : 0.0;
        bool keep = (s > s1) && (s > s2);

        bool strong = keep && (s > SQ_HI);
        bool weak = keep && (s > SQ_LO) && !strong;

        unsigned long long wb = __ballot(weak);
        unsigned long long sb = __ballot(strong);
        if ((tid & 31) == 0) {
            unsigned int ww = (tid & 32) ? (unsigned int)(wb >> 32) : (unsigned int)wb;
            unsigned int sw = (tid & 32) ? (unsigned int)(sb >> 32) : (unsigned int)sb;
            size_t w32 = ((size_t)k * HW + (size_t)gy * WW + tx0) >> 5;
            weakb[w32] = ww;
            strongb[w32] = sw;
        }
    }
}

// ---------------- Kernel 2: hysteresis closure on bitmaps ----------------
// One block per channel; strong bitmap in LDS; monotone 3x3 bitwise dilation
// through the weak mask until fixed point (== reference while_loop fixed point).
__global__ __launch_bounds__(1024) void hyst_iterate(const unsigned int* __restrict__ weakb,
                                                     unsigned int* __restrict__ strongb) {
    int k = blockIdx.x;
    __shared__ unsigned int Sm[WORDS];
    __shared__ int s_changed;
    int tid = threadIdx.x;

    const unsigned int* wsrc = weakb + (size_t)k * WORDS;
    unsigned int* ssrc = strongb + (size_t)k * WORDS;

    if (tid == 0) s_changed = 0;
    for (int i = tid; i < WORDS; i += 1024) Sm[i] = ssrc[i];
    unsigned int wreg[8];
    #pragma unroll
    for (int q = 0; q < 8; q++) wreg[q] = wsrc[tid * 8 + q];
    __syncthreads();

    for (;;) {
        int loc = 0;
        #pragma unroll
        for (int q = 0; q < 8; q++) {
            int w = tid * 8 + q;
            unsigned int s = Sm[w];
            unsigned int wk = wreg[q] & ~s;
            if (!wk) continue;
            int j = w & 15;  // word column within 16-word row
            unsigned int L = j ? Sm[w - 1] : 0u;
            unsigned int R = (j < 15) ? Sm[w + 1] : 0u;
            unsigned int D = (s << 1) | (L >> 31) | (s >> 1) | (R << 31);
            if (w >= 16) {
                unsigned int cu = Sm[w - 16];
                unsigned int Lu = j ? Sm[w - 17] : 0u;
                unsigned int Ru = (j < 15) ? Sm[w - 15] : 0u;
                D |= cu | (cu << 1) | (Lu >> 31) | (cu >> 1) | (Ru << 31);
            }
            if (w < WORDS - 16) {
                unsigned int cd = Sm[w + 16];
                unsigned int Ld = j ? Sm[w + 15] : 0u;
                unsigned int Rd = (j < 15) ? Sm[w + 17] : 0u;
                D |= cd | (cd << 1) | (Ld >> 31) | (cd >> 1) | (Rd << 31);
            }
            unsigned int promoted = wk & D;
            if (promoted) { Sm[w] = s | promoted; loc = 1; }
        }
        if (loc) s_changed = 1;
        __syncthreads();
        int chg = s_changed;
        __syncthreads();
        if (!chg) break;
        if (tid == 0) s_changed = 0;
        __syncthreads();
    }

    for (int i = tid; i < WORDS; i += 1024) ssrc[i] = Sm[i];
}

// ---------------- Kernel 3: out = x[:,indices] * tf, full grid, float4 ----------------
__global__ void mul_kernel(const float* __restrict__ x,
                           const int* __restrict__ idx,
                           const unsigned int* __restrict__ weakb,
                           const unsigned int* __restrict__ strongb,
                           float* __restrict__ out) {
    int gid = blockIdx.x * blockDim.x + threadIdx.x;
    int p = gid * 4;
    if (p >= KCH * HW) return;
    int k = p >> 18;
    int r = p & (HW - 1);
    int ch = idx[k];

    unsigned int sw = strongb[p >> 5];
    unsigned int ww = weakb[p >> 5];
    int b0 = p & 31;

    const float4 xv = *reinterpret_cast<const float4*>(x + (size_t)ch * HW + r);
    float t[4];
    #pragma unroll
    for (int i = 0; i < 4; i++) {
        int b = b0 + i;
        t[i] = ((sw >> b) & 1u) ? 1.0f : (((ww >> b) & 1u) ? 0.5f : 0.0f);
    }
    float4 o;
    o.x = xv.x * t[0];
    o.y = xv.y * t[1];
    o.z = xv.z * t[2];
    o.w = xv.w * t[3];
    *reinterpret_cast<float4*>(out + (size_t)p) = o;
}

extern "C" void kernel_launch(void* const* d_in, const int* in_sizes, int n_in,
                              void* d_out, int out_size, void* d_ws, size_t ws_size,
                              hipStream_t stream) {
    const float* x = (const float*)d_in[0];
    // d_in[1] = params (always 1 here; params==0 changes output shape, impossible
    // given out_size)
    const int* idx = (const int*)d_in[2];
    float* out = (float*)d_out;

    char* ws = (char*)d_ws;
    unsigned int* weakb = (unsigned int*)ws;                 // 1 MB
    unsigned int* strongb = (unsigned int*)(ws + 1048576);   // 1 MB

    int ntiles = KCH * NT * NT;  // 32 * 256 = 8192
    canny_fused<<<ntiles, 256, 0, stream>>>(x, idx, weakb, strongb);
    hyst_iterate<<<KCH, 1024, 0, stream>>>(weakb, strongb);
    mul_kernel<<<(KCH * HW / 4) / 256, 256, 0, stream>>>(x, idx, weakb, strongb, out);
}